// Round 15
// baseline (229.558 us; speedup 1.0000x reference)
//
#include <hip/hip_runtime.h>
#include <hip/hip_bf16.h>
#include <stdint.h>

typedef __attribute__((ext_vector_type(8))) short short8;
typedef __attribute__((ext_vector_type(4))) float f32x4;
typedef __attribute__((ext_vector_type(4))) unsigned short ushort4v;
typedef __attribute__((ext_vector_type(4))) unsigned int uint4v;

#define NB 32
#define NS 512
#define NE 256
#define NH2 128
#define NG 512
#define NT 22

__device__ __forceinline__ unsigned short f2bf(float f) {
    union { float f; unsigned u; } v; v.f = f;
    unsigned r = v.u + 0x7fffu + ((v.u >> 16) & 1u);
    return (unsigned short)(r >> 16);
}
__device__ __forceinline__ float bf2f(unsigned short b) {
    union { unsigned u; float f; } v; v.u = ((unsigned)b) << 16;
    return v.f;
}
__device__ __forceinline__ unsigned cvt_pk_bf16(float a, float b) {
    unsigned r;
    asm("v_cvt_pk_bf16_f32 %0, %1, %2" : "=v"(r) : "v"(a), "v"(b));
    return r;
}
__device__ __forceinline__ void wg_barrier() {
    __builtin_amdgcn_sched_barrier(0);
    asm volatile("s_waitcnt lgkmcnt(0)" ::: "memory");
    __builtin_amdgcn_s_barrier();
    __builtin_amdgcn_sched_barrier(0);
}
#define GL16(gsrc, ldst)                                                              \
    __builtin_amdgcn_global_load_lds(                                                 \
        (const __attribute__((address_space(1))) unsigned int*)(gsrc),                \
        (__attribute__((address_space(3))) unsigned int*)(ldst), 16, 0, 0)

// ---------------- pre: emb gather+cvt, weight conversions, Y copy, counter reset ----------------
__global__ void k_pre(const int* X, const float* emb, const int* Y,
                      const float* Wih_f, const float* Wih_b,
                      const float* Whh_f, const float* Whh_b, const float* fcW,
                      unsigned short* ebf, unsigned short* Wb_ih,
                      unsigned short* Wb_hh, unsigned short* fcpad, float* out,
                      unsigned* done_cnt)
{
    int idx = blockIdx.x * blockDim.x + threadIdx.x;
    if (idx == 0) *done_cnt = 0;
    const int nEmb = NB * NS * 64;
    if (idx < nEmb) {
        int r = idx >> 6, lane = idx & 63;
        int xr = X[r];
        f32x4 v = *(const f32x4*)(emb + (size_t)xr * NE + lane * 4);
        ushort4v o;
        o[0] = f2bf(v[0]); o[1] = f2bf(v[1]); o[2] = f2bf(v[2]); o[3] = f2bf(v[3]);
        *(ushort4v*)(ebf + (size_t)r * NE + lane * 4) = o;
        return;
    }
    int j = idx - nEmb;
    const int n1 = 2 * NG * NE;
    const int n2 = 2 * NG * NH2;
    const int n3 = 2 * 32 * NH2;
    const int n4 = NB * NS;
    if (j < n1) {
        const float* src = (j < NG * NE) ? Wih_f : Wih_b;
        Wb_ih[j] = f2bf(src[j % (NG * NE)]);
    } else if (j < n1 + n2) {
        int i2 = j - n1;
        const float* src = (i2 < NG * NH2) ? Whh_f : Whh_b;
        Wb_hh[i2] = f2bf(src[i2 % (NG * NH2)]);
    } else if (j < n1 + n2 + n3) {
        int i3 = j - n1 - n2;
        int d = i3 / (32 * NH2);
        int jj = (i3 / NH2) % 32;
        int k = i3 % NH2;
        fcpad[i3] = (jj < NT) ? f2bf(fcW[jj * 256 + d * NH2 + k]) : (unsigned short)0;
    } else if (j < n1 + n2 + n3 + n4) {
        int i4 = j - n1 - n2 - n3;
        out[1 + i4] = (float)Y[i4];
    }
}

// ---------------- input projection GEMM: double-buffered LDS staging ----------------
// Xp[dir][sb(32)][t(32)][g(512)][16 s]  (slot = 8192 bf16 = 16KB)
__launch_bounds__(256)
__global__ void k_xproj(const unsigned short* ebf, const unsigned short* Wb_ih,
                        const float* bih_f, const float* bhh_f,
                        const float* bih_b, const float* bhh_b,
                        unsigned short* Xp)
{
    __shared__ __align__(16) unsigned short Atile[2][128 * 64];
    __shared__ __align__(16) unsigned short Btile[2][128 * 64];
    int dir = blockIdx.z;
    int r0 = blockIdx.x * 128;
    int g0 = blockIdx.y * 128;
    int tid = threadIdx.x;
    int w = tid >> 6, lane = tid & 63;
    int wr = w >> 1, wc = w & 1;
    int lrow = lane & 15, kg = lane >> 4;
    int srow8 = lane >> 3, schunk = lane & 7;
    const float* bih = dir ? bih_b : bih_f;
    const float* bhh = dir ? bhh_b : bhh_f;
    const unsigned short* Bsrc = Wb_ih + ((size_t)dir * NG + g0) * NE;
    const unsigned short* Asrc = ebf + (size_t)r0 * NE;

#define STAGE(bufi, ks)                                                                \
    do {                                                                               \
        int k0_ = (ks) * 64;                                                           \
        _Pragma("unroll")                                                              \
        for (int i_ = 0; i_ < 4; ++i_) {                                               \
            int rr_ = (w * 4 + i_) * 8 + srow8;                                        \
            GL16(Asrc + (size_t)rr_ * NE + k0_ + schunk * 8, &Atile[bufi][(w * 4 + i_) * 512]); \
            GL16(Bsrc + (size_t)rr_ * NE + k0_ + schunk * 8, &Btile[bufi][(w * 4 + i_) * 512]); \
        }                                                                              \
    } while (0)

    STAGE(0, 0);
    f32x4 acc[4][4] = {};
#pragma unroll
    for (int ks = 0; ks < 4; ++ks) {
        const int cur = ks & 1;
        if (ks < 3) {
            STAGE(cur ^ 1, ks + 1);
            asm volatile("s_waitcnt vmcnt(8)" ::: "memory");
        } else {
            asm volatile("s_waitcnt vmcnt(0)" ::: "memory");
        }
        __builtin_amdgcn_sched_barrier(0);
        __builtin_amdgcn_s_barrier();
        __builtin_amdgcn_sched_barrier(0);
        short8 a[4][2], b[4][2];
#pragma unroll
        for (int mi = 0; mi < 4; ++mi)
#pragma unroll
            for (int kk = 0; kk < 2; ++kk)
                a[mi][kk] = *(const short8*)&Atile[cur][(wr * 64 + mi * 16 + lrow) * 64 + kk * 32 + kg * 8];
#pragma unroll
        for (int ni = 0; ni < 4; ++ni)
#pragma unroll
            for (int kk = 0; kk < 2; ++kk)
                b[ni][kk] = *(const short8*)&Btile[cur][(wc * 64 + ni * 16 + lrow) * 64 + kk * 32 + kg * 8];
#pragma unroll
        for (int mi = 0; mi < 4; ++mi)
#pragma unroll
            for (int ni = 0; ni < 4; ++ni)
#pragma unroll
                for (int kk = 0; kk < 2; ++kk)
                    acc[mi][ni] = __builtin_amdgcn_mfma_f32_16x16x32_bf16(a[mi][kk], b[ni][kk], acc[mi][ni], 0, 0, 0);
        asm volatile("s_waitcnt lgkmcnt(0)" ::: "memory");
        __builtin_amdgcn_sched_barrier(0);
        __builtin_amdgcn_s_barrier();
        __builtin_amdgcn_sched_barrier(0);
    }
#undef STAGE

#pragma unroll
    for (int ni = 0; ni < 4; ++ni) {
        int g = g0 + wc * 64 + ni * 16 + lrow;
        float bias = bih[g] + bhh[g];
#pragma unroll
        for (int mi = 0; mi < 4; ++mi) {
            int r = r0 + wr * 64 + mi * 16 + kg * 4;
            int t = r >> 9;
            int s = r & 511;
            int sb = s >> 4;
            unsigned short* dst = Xp + ((((size_t)dir * 32 + sb) * 32 + t) << 13) + g * 16 + (s & 15);
            unsigned o0 = f2bf(acc[mi][ni][0] + bias);
            unsigned o1 = f2bf(acc[mi][ni][1] + bias);
            unsigned o2 = f2bf(acc[mi][ni][2] + bias);
            unsigned o3 = f2bf(acc[mi][ni][3] + bias);
            uint2 pk; pk.x = o0 | (o1 << 16); pk.y = o2 | (o3 << 16);
            *(uint2*)dst = pk;
        }
    }
}

// ---------------- LSTM v7b: both dirs in one 1024-thr block (waves 0-7=dir0, 8-15=dir1).
// Per-wave state identical to v5; FC results stored directly to global featsP (no featsL),
// keeping static LDS at 17.4 KB (< 64 KB block limit — v7's 66.5 KB failed to launch).
__launch_bounds__(1024, 1)
__global__ void k_lstm(const unsigned short* Wb_hh, const unsigned short* fcpad,
                       const unsigned short* Xp, const float* h0, const float* c0,
                       unsigned short* featsP)
{
    __shared__ unsigned short h_lds[2][2][16 * 136];   // [dir][buf] 17408 B
    int sb = blockIdx.x;
    int s0 = sb * 16;
    int tid = threadIdx.x;
    int w = tid >> 6, lane = tid & 63;
    int dirv = w >> 3;           // wave-uniform: 0 for waves 0-7, 1 for waves 8-15
    int wl = w & 7;              // local wave index within the chain
    int lrow = lane & 15, kg = lane >> 4;

    short8 bfr[4][4];
#pragma unroll
    for (int q = 0; q < 4; ++q) {
        const unsigned short* p = Wb_hh + ((size_t)dirv * NG + (q * 128 + wl * 16 + lrow)) * NH2 + kg * 8;
#pragma unroll
        for (int kf = 0; kf < 4; ++kf)
            bfr[q][kf] = *(const short8*)(p + kf * 32);
    }
    short8 fcfr[4];
    if (wl < 2) {
        const unsigned short* p = fcpad + ((size_t)dirv * 32 + (wl * 16 + lrow)) * NH2 + kg * 8;
#pragma unroll
        for (int kf = 0; kf < 4; ++kf)
            fcfr[kf] = *(const short8*)(p + kf * 32);
    }

    float c[4], ho[4];
#pragma unroll
    for (int i = 0; i < 4; ++i)
        c[i] = c0[((size_t)dirv * NS + s0 + kg * 4 + i) * NH2 + wl * 16 + lrow];
    {
        int tidh = tid & 511;
        int sl = tidh >> 5, hq = tidh & 31;
        f32x4 hv = *(const f32x4*)(h0 + ((size_t)dirv * NS + s0 + sl) * NH2 + hq * 4);
        ushort4v hb; hb[0] = f2bf(hv[0]); hb[1] = f2bf(hv[1]); hb[2] = f2bf(hv[2]); hb[3] = f2bf(hv[3]);
        *(ushort4v*)&h_lds[dirv][0][sl * 136 + hq * 4] = hb;
    }

    const unsigned short* xbase = Xp + (((size_t)dirv * 32 + sb) * 32) * 8192;
    int xoff0 = (wl * 16 + lrow) * 16 + kg * 4;
    ushort4v xA[4], xB[4];
#pragma unroll
    for (int q = 0; q < 4; ++q)
        xA[q] = *(const ushort4v*)(xbase + (size_t)(dirv ? 31 : 0) * 8192 + xoff0 + q * 2048);
#pragma unroll
    for (int q = 0; q < 4; ++q)
        xB[q] = *(const ushort4v*)(xbase + (size_t)(dirv ? 30 : 1) * 8192 + xoff0 + q * 2048);
    __syncthreads();

#define LSTM_STEP(T, XV, PR, PW)                                                       \
    {                                                                                  \
        short8 afr[4];                                                                 \
        _Pragma("unroll")                                                              \
        for (int kf = 0; kf < 4; ++kf)                                                 \
            afr[kf] = *(const short8*)&h_lds[dirv][PR][lrow * 136 + kf * 32 + kg * 8]; \
        f32x4 accA[4], accB[4];                                                        \
        _Pragma("unroll")                                                              \
        for (int q = 0; q < 4; ++q) {                                                  \
            f32x4 ci_;                                                                 \
            ci_[0] = bf2f(XV[q][0]); ci_[1] = bf2f(XV[q][1]);                          \
            ci_[2] = bf2f(XV[q][2]); ci_[3] = bf2f(XV[q][3]);                          \
            accA[q] = __builtin_amdgcn_mfma_f32_16x16x32_bf16(afr[0], bfr[q][0], ci_, 0, 0, 0); \
            f32x4 z_ = {};                                                             \
            accB[q] = __builtin_amdgcn_mfma_f32_16x16x32_bf16(afr[2], bfr[q][2], z_, 0, 0, 0);  \
        }                                                                              \
        _Pragma("unroll")                                                              \
        for (int q = 0; q < 4; ++q) {                                                  \
            accA[q] = __builtin_amdgcn_mfma_f32_16x16x32_bf16(afr[1], bfr[q][1], accA[q], 0, 0, 0); \
            accB[q] = __builtin_amdgcn_mfma_f32_16x16x32_bf16(afr[3], bfr[q][3], accB[q], 0, 0, 0); \
        }                                                                              \
        if (wl < 2 && (T) > 0) {   /* FC of h(step T-1), held in afr -> global */      \
            int txp_ = dirv ? 32 - (T) : (T) - 1;                                      \
            f32x4 fa_ = {};                                                            \
            _Pragma("unroll")                                                          \
            for (int kf = 0; kf < 4; ++kf)                                             \
                fa_ = __builtin_amdgcn_mfma_f32_16x16x32_bf16(afr[kf], fcfr[kf], fa_, 0, 0, 0); \
            int tag_ = wl * 16 + lrow;                                                 \
            if (tag_ < NT) {                                                           \
                _Pragma("unroll")                                                      \
                for (int i = 0; i < 4; ++i)                                            \
                    featsP[(((size_t)dirv * 32 + txp_) * 512 + s0 + kg * 4 + i) * 24 + tag_] = f2bf(fa_[i]); \
            }                                                                          \
        }                                                                              \
        if ((T) + 2 < 32) {                                                            \
            int txn = dirv ? 29 - (T) : (T) + 2;                                       \
            _Pragma("unroll")                                                          \
            for (int q = 0; q < 4; ++q)                                                \
                XV[q] = *(const ushort4v*)(xbase + (size_t)txn * 8192 + xoff0 + q * 2048); \
        }                                                                              \
        _Pragma("unroll")                                                              \
        for (int i = 0; i < 4; ++i) {                                                  \
            float gi_ = accA[0][i] + accB[0][i];                                       \
            float gf_ = accA[1][i] + accB[1][i];                                       \
            float gg_ = accA[2][i] + accB[2][i];                                       \
            float go_ = accA[3][i] + accB[3][i];                                       \
            float ef_ = __expf(-gf_);                                                  \
            float sfc_ = c[i] * __builtin_amdgcn_rcpf(1.f + ef_);                      \
            float eg2_ = __expf(2.f * gg_);                                            \
            float ei_ = __expf(-gi_);                                                  \
            float tgsi_ = (eg2_ - 1.f) * __builtin_amdgcn_rcpf((1.f + ei_) * (eg2_ + 1.f)); \
            float cn_ = sfc_ + tgsi_;                                                  \
            c[i] = cn_;                                                                \
            float ec2_ = __expf(2.f * cn_);                                            \
            float eo_ = __expf(-go_);                                                  \
            ho[i] = (ec2_ - 1.f) * __builtin_amdgcn_rcpf((1.f + eo_) * (ec2_ + 1.f));  \
        }                                                                              \
        {                                                                              \
            unsigned r01_ = cvt_pk_bf16(ho[0], ho[1]);                                 \
            unsigned r23_ = cvt_pk_bf16(ho[2], ho[3]);                                 \
            int hb_ = (kg * 4) * 136 + wl * 16 + lrow;                                 \
            h_lds[dirv][PW][hb_]       = (unsigned short)r01_;                         \
            h_lds[dirv][PW][hb_ + 136] = (unsigned short)(r01_ >> 16);                 \
            h_lds[dirv][PW][hb_ + 272] = (unsigned short)r23_;                         \
            h_lds[dirv][PW][hb_ + 408] = (unsigned short)(r23_ >> 16);                 \
        }                                                                              \
        wg_barrier();                                                                  \
    }

    for (int tt = 0; tt < 16; ++tt) {
        LSTM_STEP(2 * tt,     xA, ((2 * tt) & 1),     (((2 * tt) & 1) ^ 1))
        LSTM_STEP(2 * tt + 1, xB, ((2 * tt + 1) & 1), (((2 * tt + 1) & 1) ^ 1))
    }
#undef LSTM_STEP

    // FC for the final h (in h_lds[dirv][0] after step 31)
    if (wl < 2) {
        short8 afr[4];
#pragma unroll
        for (int kf = 0; kf < 4; ++kf)
            afr[kf] = *(const short8*)&h_lds[dirv][0][lrow * 136 + kf * 32 + kg * 8];
        f32x4 fa = {};
#pragma unroll
        for (int kf = 0; kf < 4; ++kf)
            fa = __builtin_amdgcn_mfma_f32_16x16x32_bf16(afr[kf], fcfr[kf], fa, 0, 0, 0);
        int txl = dirv ? 0 : 31;
        int tag = wl * 16 + lrow;
        if (tag < NT) {
#pragma unroll
            for (int i = 0; i < 4; ++i)
                featsP[(((size_t)dirv * 32 + txl) * 512 + s0 + kg * 4 + i) * 24 + tag] = f2bf(fa[i]);
        }
    }
}

// ---------------- CRF helpers ----------------
__device__ __forceinline__ float mm_combine(const unsigned short* Rb, const unsigned short* Tb,
                                            int lane, f32x4 c[2][2])
{
    int lrow = lane & 15, kg = lane >> 4;
    short8 a0 = *(const short8*)(Rb + lrow * 32 + kg * 8);
    short8 a1 = *(const short8*)(Rb + (16 + lrow) * 32 + kg * 8);
    short8 b0 = *(const short8*)(Tb + lrow * 32 + kg * 8);
    short8 b1 = *(const short8*)(Tb + (16 + lrow) * 32 + kg * 8);
    c[0][0] = __builtin_amdgcn_mfma_f32_16x16x32_bf16(a0, b0, c[0][0], 0, 0, 0);
    c[0][1] = __builtin_amdgcn_mfma_f32_16x16x32_bf16(a0, b1, c[0][1], 0, 0, 0);
    c[1][0] = __builtin_amdgcn_mfma_f32_16x16x32_bf16(a1, b0, c[1][0], 0, 0, 0);
    c[1][1] = __builtin_amdgcn_mfma_f32_16x16x32_bf16(a1, b1, c[1][1], 0, 0, 0);
    float mx = 0.f;
#pragma unroll
    for (int ti = 0; ti < 2; ++ti)
#pragma unroll
        for (int tj = 0; tj < 2; ++tj)
#pragma unroll
            for (int i = 0; i < 4; ++i) mx = fmaxf(mx, c[ti][tj][i]);
#pragma unroll
    for (int off = 32; off; off >>= 1) mx = fmaxf(mx, __shfl_xor(mx, off));
    return fmaxf(mx, 1e-30f);
}

__device__ __forceinline__ void write_scaled(unsigned short* outp, bool Rlayout,
                                             int lane, const f32x4 c[2][2], float inv)
{
    int lrow = lane & 15, kg = lane >> 4;
    if (Rlayout) {
#pragma unroll
        for (int ti = 0; ti < 2; ++ti)
#pragma unroll
            for (int tj = 0; tj < 2; ++tj) {
                int cc = tj * 16 + lrow;
#pragma unroll
                for (int i = 0; i < 4; ++i) {
                    int r = ti * 16 + kg * 4 + i;
                    float v = (r < NT && cc < NT) ? c[ti][tj][i] * inv : 0.f;
                    outp[r * 32 + cc] = f2bf(v);
                }
            }
    } else {
#pragma unroll
        for (int ti = 0; ti < 2; ++ti)
#pragma unroll
            for (int tj = 0; tj < 2; ++tj) {
                int cc = tj * 16 + lrow;
                int r0 = ti * 16 + kg * 4;
                ushort4v pk;
#pragma unroll
                for (int i = 0; i < 4; ++i) {
                    int r = r0 + i;
                    float v = (r < NT && cc < NT) ? c[ti][tj][i] * inv : 0.f;
                    pk[i] = f2bf(v);
                }
                *(ushort4v*)(outp + cc * 32 + r0) = pk;
            }
    }
}

// block (b=chain, seg): bf16 featsP -> ef/fl, gold partial, 16 leaves -> seg matrix
__launch_bounds__(256)
__global__ void k_fcrf(const unsigned short* featsP, const float* fcb, const float* trans,
                       const int* Y, unsigned short* Mseg, float* lscseg, float* goldp)
{
    __shared__ unsigned short mats[16 * 1024];
    __shared__ float etR[484], etT[484];
    __shared__ float ef[16 * 24];
    __shared__ float fl[16 * 24];
    __shared__ float lscm[16];
    int b = blockIdx.x, seg = blockIdx.y;
    int tid = threadIdx.x;
    int w = tid >> 6, lane = tid & 63;

    for (int i = tid; i < 484; i += 256) {
        float e = __expf(trans[i]);
        etR[i] = e;
        etT[(i % NT) * NT + (i / NT)] = e;
    }
    for (int i = tid; i < 16 * NT; i += 256) {
        int s = i / NT, j = i % NT;
        size_t base = ((size_t)b * 512 + seg * 16 + s) * 24 + j;
        float f = bf2f(featsP[base]) + bf2f(featsP[(size_t)32 * 512 * 24 + base]) + fcb[j];
        fl[s * 24 + j] = f;
        ef[s * 24 + j] = __expf(f);
    }
    if (tid < 16) lscm[tid] = 0.f;
    __syncthreads();

    if (w == 3 && lane < 16) {
        int sg = seg * 16 + lane;
        int y = Y[b * NS + sg];
        int yp = sg ? Y[b * NS + sg - 1] : (NT - 2);
        float gp = fl[lane * 24 + y] + trans[y * NT + yp];
#pragma unroll
        for (int off = 8; off; off >>= 1) gp += __shfl_xor(gp, off);
        if (lane == 0) goldp[b * 32 + seg] = gp;
    }

    // vectorized leaf build: 2 bf16 per thread-iter
    for (int u = tid; u < 16 * 512; u += 256) {
        int t = u >> 9, cell2 = u & 511, row = cell2 >> 4, col = (cell2 & 15) * 2;
        float v0 = 0.f, v1 = 0.f;
        if (row < NT) {
            if (t & 1) {
                if (col < NT)     v0 = etR[row * NT + col]     * ef[t * 24 + row];
                if (col + 1 < NT) v1 = etR[row * NT + col + 1] * ef[t * 24 + row];
            } else {
                if (col < NT)     v0 = etT[row * NT + col]     * ef[t * 24 + col];
                if (col + 1 < NT) v1 = etT[row * NT + col + 1] * ef[t * 24 + col + 1];
            }
        }
        ((unsigned*)mats)[u] = (unsigned)f2bf(v0) | ((unsigned)f2bf(v1) << 16);
    }
    __syncthreads();

    for (int lvl = 0; lvl < 4; ++lvl) {
        int nP = 8 >> lvl;
        for (int p = w; p < nP; p += 4) {
            int aslot = (2 * p) << lvl, bslot = (2 * p + 1) << lvl;
            f32x4 c[2][2] = {};
            float mx = mm_combine(mats + bslot * 1024, mats + aslot * 1024, lane, c);
            float inv = __builtin_amdgcn_rcpf(mx);
            float nlsc = lscm[aslot] + lscm[bslot] + __logf(mx);
            if (lvl < 3) {
                write_scaled(mats + aslot * 1024, (p & 1) != 0, lane, c, inv);
                if (lane == 0) lscm[aslot] = nlsc;
            } else {
                write_scaled(Mseg + ((size_t)b * 32 + seg) * 1024, (seg & 1) != 0, lane, c, inv);
                if (lane == 0) lscseg[b * 32 + seg] = nlsc;
            }
        }
        __syncthreads();
    }
}

// final stage fused: 32 matrices -> score; last finished block writes out[0]
__launch_bounds__(256)
__global__ void k_crf2(const unsigned short* Mseg, const float* lscseg,
                       const float* trans, const int* Y, const float* goldp,
                       float* fwd_sc, float* gold_sc, unsigned* done_cnt, float* out)
{
    __shared__ unsigned short mats[16 * 1024];
    __shared__ float lscm[16];
    __shared__ float tl[484];
    __shared__ float col20[32];
    __shared__ unsigned lastflag;
    int b = blockIdx.x;
    int tid = threadIdx.x;
    int w = tid >> 6, lane = tid & 63;
    int lrow = lane & 15, kg = lane >> 4;

    for (int i = tid; i < 484; i += 256) tl[i] = trans[i];
    __syncthreads();

    const unsigned short* base = Mseg + (size_t)b * 32 * 1024;
    for (int p = w; p < 16; p += 4) {
        f32x4 c[2][2] = {};
        float mx = mm_combine(base + (2 * p + 1) * 1024, base + (2 * p) * 1024, lane, c);
        float inv = __builtin_amdgcn_rcpf(mx);
        float nlsc = lscseg[b * 32 + 2 * p] + lscseg[b * 32 + 2 * p + 1] + __logf(mx);
        write_scaled(mats + p * 1024, (p & 1) != 0, lane, c, inv);
        if (lane == 0) lscm[p] = nlsc;
    }
    __syncthreads();

    for (int lvl = 0; lvl < 4; ++lvl) {
        int nP = 8 >> lvl;
        for (int p = w; p < nP; p += 4) {
            int aslot = (2 * p) << lvl, bslot = (2 * p + 1) << lvl;
            f32x4 c[2][2] = {};
            float mx = mm_combine(mats + bslot * 1024, mats + aslot * 1024, lane, c);
            if (lvl < 3) {
                float inv = __builtin_amdgcn_rcpf(mx);
                float nlsc = lscm[aslot] + lscm[bslot] + __logf(mx);
                write_scaled(mats + aslot * 1024, (p & 1) != 0, lane, c, inv);
                if (lane == 0) lscm[aslot] = nlsc;
            } else {
                if (lrow == 4) {
#pragma unroll
                    for (int ti = 0; ti < 2; ++ti)
#pragma unroll
                        for (int i = 0; i < 4; ++i)
                            col20[ti * 16 + kg * 4 + i] = c[ti][1][i];
                }
                if (lane == 0) lscm[0] = lscm[0] + lscm[8];
            }
        }
        __syncthreads();
    }

    if (w == 0) {
        float v = 0.f;
        if (lane < NT) v = __expf(tl[(NT - 1) * NT + lane]) * col20[lane];
#pragma unroll
        for (int off = 32; off; off >>= 1) v += __shfl_xor(v, off);
        if (lane == 0) fwd_sc[b] = __logf(v) + lscm[0];
    }
    if (w == 1) {
        float g = (lane < 32) ? goldp[b * 32 + lane] : 0.f;
#pragma unroll
        for (int off = 16; off; off >>= 1) g += __shfl_xor(g, off);
        if (lane == 0) gold_sc[b] = g + tl[(NT - 1) * NT + Y[b * NS + NS - 1]];
    }
    // completion: last block computes the mean
    __syncthreads();
    if (tid == 0) {
        __threadfence();
        lastflag = (atomicAdd(done_cnt, 1u) == 31u) ? 1u : 0u;
    }
    __syncthreads();
    if (lastflag && w == 0) {
        __threadfence();
        float v = (lane < NB) ? (fwd_sc[lane] - gold_sc[lane]) : 0.f;
#pragma unroll
        for (int off = 32; off; off >>= 1) v += __shfl_xor(v, off);
        if (lane == 0) out[0] = v * (1.f / NB);
    }
}

extern "C" void kernel_launch(void* const* d_in, const int* in_sizes, int n_in,
                              void* d_out, int out_size, void* d_ws, size_t ws_size,
                              hipStream_t stream)
{
    const int* X = (const int*)d_in[0];
    const int* Y = (const int*)d_in[1];
    const float* emb = (const float*)d_in[2];
    const float* Wih_f = (const float*)d_in[3];
    const float* Whh_f = (const float*)d_in[4];
    const float* bih_f = (const float*)d_in[5];
    const float* bhh_f = (const float*)d_in[6];
    const float* Wih_b = (const float*)d_in[7];
    const float* Whh_b = (const float*)d_in[8];
    const float* bih_b = (const float*)d_in[9];
    const float* bhh_b = (const float*)d_in[10];
    const float* fcW = (const float*)d_in[11];
    const float* fcb = (const float*)d_in[12];
    const float* trans = (const float*)d_in[13];
    const float* h0 = (const float*)d_in[14];
    const float* c0 = (const float*)d_in[15];
    float* out = (float*)d_out;

    char* ws = (char*)d_ws;
    unsigned short* Wb_ih  = (unsigned short*)(ws + 0);          // 524288 B
    unsigned short* Wb_hh  = (unsigned short*)(ws + 524288);     // 262144 B
    unsigned short* fcpad  = (unsigned short*)(ws + 786432);     // 16384 B
    unsigned short* Xp     = (unsigned short*)(ws + 802816);     // 33554432 B
    unsigned short* featsP = (unsigned short*)(ws + 34357248);   // 1572864 B (bf16)
    float* goldp           = (float*)(ws + 35930112);            // 4096 B
    float* fwd_sc          = (float*)(ws + 35934208);            // 128 B
    float* gold_sc         = (float*)(ws + 35934336);            // 128 B
    unsigned* done_cnt     = (unsigned*)(ws + 35934464);         // 128 B
    unsigned short* ebf    = (unsigned short*)(ws + 35934592);   // 8388608 B
    unsigned short* Mseg   = ebf;                                // (ebf dead after k_xproj)
    float* lscseg          = (float*)(ws + 44323200);            // 4096 B (total ~44.3 MB)

    k_pre<<<dim3(5728), dim3(256), 0, stream>>>(X, emb, Y, Wih_f, Wih_b, Whh_f, Whh_b,
                                                fcW, ebf, Wb_ih, Wb_hh, fcpad, out, done_cnt);
    k_xproj<<<dim3(128, 4, 2), dim3(256), 0, stream>>>(ebf, Wb_ih, bih_f, bhh_f, bih_b, bhh_b, Xp);
    k_lstm<<<dim3(32), dim3(1024), 0, stream>>>(Wb_hh, fcpad, Xp, h0, c0, featsP);
    k_fcrf<<<dim3(32, 32), dim3(256), 0, stream>>>(featsP, fcb, trans, Y, Mseg, lscseg, goldp);
    k_crf2<<<dim3(NB), dim3(256), 0, stream>>>(Mseg, lscseg, trans, Y, goldp,
                                               fwd_sc, gold_sc, done_cnt, out);
    (void)in_sizes; (void)n_in; (void)out_size; (void)ws_size;
}

// Round 16
// 93.563 us; speedup vs baseline: 2.4535x; 2.4535x over previous
//
#include <hip/hip_runtime.h>
#include <hip/hip_bf16.h>
#include <stdint.h>

typedef __attribute__((ext_vector_type(8))) short short8;
typedef __attribute__((ext_vector_type(4))) float f32x4;
typedef __attribute__((ext_vector_type(4))) unsigned short ushort4v;
typedef __attribute__((ext_vector_type(4))) unsigned int uint4v;

#define NB 32
#define NS 512
#define NE 256
#define NH2 128
#define NG 512
#define NT 22

__device__ __forceinline__ unsigned short f2bf(float f) {
    union { float f; unsigned u; } v; v.f = f;
    unsigned r = v.u + 0x7fffu + ((v.u >> 16) & 1u);
    return (unsigned short)(r >> 16);
}
__device__ __forceinline__ float bf2f(unsigned short b) {
    union { unsigned u; float f; } v; v.u = ((unsigned)b) << 16;
    return v.f;
}
__device__ __forceinline__ unsigned cvt_pk_bf16(float a, float b) {
    unsigned r;
    asm("v_cvt_pk_bf16_f32 %0, %1, %2" : "=v"(r) : "v"(a), "v"(b));
    return r;
}
__device__ __forceinline__ void wg_barrier() {
    __builtin_amdgcn_sched_barrier(0);
    asm volatile("s_waitcnt lgkmcnt(0)" ::: "memory");
    __builtin_amdgcn_s_barrier();
    __builtin_amdgcn_sched_barrier(0);
}
#define GL16(gsrc, ldst)                                                              \
    __builtin_amdgcn_global_load_lds(                                                 \
        (const __attribute__((address_space(1))) unsigned int*)(gsrc),                \
        (__attribute__((address_space(3))) unsigned int*)(ldst), 16, 0, 0)

// ---------------- pre: emb gather+cvt, weight conversions, Y copy, counter reset ----------------
__global__ void k_pre(const int* X, const float* emb, const int* Y,
                      const float* Wih_f, const float* Wih_b,
                      const float* Whh_f, const float* Whh_b, const float* fcW,
                      unsigned short* ebf, unsigned short* Wb_ih,
                      unsigned short* Wb_hh, unsigned short* fcpad, float* out,
                      unsigned* done_cnt)
{
    int idx = blockIdx.x * blockDim.x + threadIdx.x;
    if (idx == 0) *done_cnt = 0;
    const int nEmb = NB * NS * 64;
    if (idx < nEmb) {
        int r = idx >> 6, lane = idx & 63;
        int xr = X[r];
        f32x4 v = *(const f32x4*)(emb + (size_t)xr * NE + lane * 4);
        ushort4v o;
        o[0] = f2bf(v[0]); o[1] = f2bf(v[1]); o[2] = f2bf(v[2]); o[3] = f2bf(v[3]);
        *(ushort4v*)(ebf + (size_t)r * NE + lane * 4) = o;
        return;
    }
    int j = idx - nEmb;
    const int n1 = 2 * NG * NE;
    const int n2 = 2 * NG * NH2;
    const int n3 = 2 * 32 * NH2;
    const int n4 = NB * NS;
    if (j < n1) {
        const float* src = (j < NG * NE) ? Wih_f : Wih_b;
        Wb_ih[j] = f2bf(src[j % (NG * NE)]);
    } else if (j < n1 + n2) {
        int i2 = j - n1;
        const float* src = (i2 < NG * NH2) ? Whh_f : Whh_b;
        Wb_hh[i2] = f2bf(src[i2 % (NG * NH2)]);
    } else if (j < n1 + n2 + n3) {
        int i3 = j - n1 - n2;
        int d = i3 / (32 * NH2);
        int jj = (i3 / NH2) % 32;
        int k = i3 % NH2;
        fcpad[i3] = (jj < NT) ? f2bf(fcW[jj * 256 + d * NH2 + k]) : (unsigned short)0;
    } else if (j < n1 + n2 + n3 + n4) {
        int i4 = j - n1 - n2 - n3;
        out[1 + i4] = (float)Y[i4];
    }
}

// ---------------- input projection GEMM: double-buffered LDS staging ----------------
// Xp[dir][sb(32)][t(32)][g(512)][16 s]  (slot = 8192 bf16 = 16KB)
__launch_bounds__(256)
__global__ void k_xproj(const unsigned short* ebf, const unsigned short* Wb_ih,
                        const float* bih_f, const float* bhh_f,
                        const float* bih_b, const float* bhh_b,
                        unsigned short* Xp)
{
    __shared__ __align__(16) unsigned short Atile[2][128 * 64];
    __shared__ __align__(16) unsigned short Btile[2][128 * 64];
    int dir = blockIdx.z;
    int r0 = blockIdx.x * 128;
    int g0 = blockIdx.y * 128;
    int tid = threadIdx.x;
    int w = tid >> 6, lane = tid & 63;
    int wr = w >> 1, wc = w & 1;
    int lrow = lane & 15, kg = lane >> 4;
    int srow8 = lane >> 3, schunk = lane & 7;
    const float* bih = dir ? bih_b : bih_f;
    const float* bhh = dir ? bhh_b : bhh_f;
    const unsigned short* Bsrc = Wb_ih + ((size_t)dir * NG + g0) * NE;
    const unsigned short* Asrc = ebf + (size_t)r0 * NE;

#define STAGE(bufi, ks)                                                                \
    do {                                                                               \
        int k0_ = (ks) * 64;                                                           \
        _Pragma("unroll")                                                              \
        for (int i_ = 0; i_ < 4; ++i_) {                                               \
            int rr_ = (w * 4 + i_) * 8 + srow8;                                        \
            GL16(Asrc + (size_t)rr_ * NE + k0_ + schunk * 8, &Atile[bufi][(w * 4 + i_) * 512]); \
            GL16(Bsrc + (size_t)rr_ * NE + k0_ + schunk * 8, &Btile[bufi][(w * 4 + i_) * 512]); \
        }                                                                              \
    } while (0)

    STAGE(0, 0);
    f32x4 acc[4][4] = {};
#pragma unroll
    for (int ks = 0; ks < 4; ++ks) {
        const int cur = ks & 1;
        if (ks < 3) {
            STAGE(cur ^ 1, ks + 1);
            asm volatile("s_waitcnt vmcnt(8)" ::: "memory");
        } else {
            asm volatile("s_waitcnt vmcnt(0)" ::: "memory");
        }
        __builtin_amdgcn_sched_barrier(0);
        __builtin_amdgcn_s_barrier();
        __builtin_amdgcn_sched_barrier(0);
        short8 a[4][2], b[4][2];
#pragma unroll
        for (int mi = 0; mi < 4; ++mi)
#pragma unroll
            for (int kk = 0; kk < 2; ++kk)
                a[mi][kk] = *(const short8*)&Atile[cur][(wr * 64 + mi * 16 + lrow) * 64 + kk * 32 + kg * 8];
#pragma unroll
        for (int ni = 0; ni < 4; ++ni)
#pragma unroll
            for (int kk = 0; kk < 2; ++kk)
                b[ni][kk] = *(const short8*)&Btile[cur][(wc * 64 + ni * 16 + lrow) * 64 + kk * 32 + kg * 8];
#pragma unroll
        for (int mi = 0; mi < 4; ++mi)
#pragma unroll
            for (int ni = 0; ni < 4; ++ni)
#pragma unroll
                for (int kk = 0; kk < 2; ++kk)
                    acc[mi][ni] = __builtin_amdgcn_mfma_f32_16x16x32_bf16(a[mi][kk], b[ni][kk], acc[mi][ni], 0, 0, 0);
        asm volatile("s_waitcnt lgkmcnt(0)" ::: "memory");
        __builtin_amdgcn_sched_barrier(0);
        __builtin_amdgcn_s_barrier();
        __builtin_amdgcn_sched_barrier(0);
    }
#undef STAGE

#pragma unroll
    for (int ni = 0; ni < 4; ++ni) {
        int g = g0 + wc * 64 + ni * 16 + lrow;
        float bias = bih[g] + bhh[g];
#pragma unroll
        for (int mi = 0; mi < 4; ++mi) {
            int r = r0 + wr * 64 + mi * 16 + kg * 4;
            int t = r >> 9;
            int s = r & 511;
            int sb = s >> 4;
            unsigned short* dst = Xp + ((((size_t)dir * 32 + sb) * 32 + t) << 13) + g * 16 + (s & 15);
            unsigned o0 = f2bf(acc[mi][ni][0] + bias);
            unsigned o1 = f2bf(acc[mi][ni][1] + bias);
            unsigned o2 = f2bf(acc[mi][ni][2] + bias);
            unsigned o3 = f2bf(acc[mi][ni][3] + bias);
            uint2 pk; pk.x = o0 | (o1 << 16); pk.y = o2 | (o3 << 16);
            *(uint2*)dst = pk;
        }
    }
}

// ---------------- LSTM recurrence v5 (proven best): v3 FC + split chains + merged-rcp ----------------
__launch_bounds__(512, 2)
__global__ void k_lstm(const unsigned short* Wb_hh, const unsigned short* fcpad,
                       const unsigned short* Xp, const float* h0, const float* c0,
                       unsigned short* featsP)
{
    __shared__ unsigned short h_lds[2][16 * 136];     // 8704 B
    __shared__ unsigned short featsL[512 * 24];       // 24576 B (bf16)
    int dir = blockIdx.x >> 5;
    int sb = blockIdx.x & 31;
    int s0 = sb * 16;
    int tid = threadIdx.x;
    int w = tid >> 6, lane = tid & 63;
    int lrow = lane & 15, kg = lane >> 4;

    short8 bfr[4][4];
#pragma unroll
    for (int q = 0; q < 4; ++q) {
        const unsigned short* p = Wb_hh + ((size_t)dir * NG + (q * 128 + w * 16 + lrow)) * NH2 + kg * 8;
#pragma unroll
        for (int kf = 0; kf < 4; ++kf)
            bfr[q][kf] = *(const short8*)(p + kf * 32);
    }
    short8 fcfr[4];
    if (w < 2) {
        const unsigned short* p = fcpad + ((size_t)dir * 32 + (w * 16 + lrow)) * NH2 + kg * 8;
#pragma unroll
        for (int kf = 0; kf < 4; ++kf)
            fcfr[kf] = *(const short8*)(p + kf * 32);
    }

    float c[4], ho[4];
#pragma unroll
    for (int i = 0; i < 4; ++i)
        c[i] = c0[((size_t)dir * NS + s0 + kg * 4 + i) * NH2 + w * 16 + lrow];
    {
        int sl = tid >> 5, hq = tid & 31;
        f32x4 hv = *(const f32x4*)(h0 + ((size_t)dir * NS + s0 + sl) * NH2 + hq * 4);
        ushort4v hb; hb[0] = f2bf(hv[0]); hb[1] = f2bf(hv[1]); hb[2] = f2bf(hv[2]); hb[3] = f2bf(hv[3]);
        *(ushort4v*)&h_lds[0][sl * 136 + hq * 4] = hb;
    }

    const unsigned short* xbase = Xp + (((size_t)dir * 32 + sb) * 32) * 8192;
    int xoff0 = (w * 16 + lrow) * 16 + kg * 4;
    ushort4v xA[4], xB[4];
#pragma unroll
    for (int q = 0; q < 4; ++q)
        xA[q] = *(const ushort4v*)(xbase + (size_t)(dir ? 31 : 0) * 8192 + xoff0 + q * 2048);
#pragma unroll
    for (int q = 0; q < 4; ++q)
        xB[q] = *(const ushort4v*)(xbase + (size_t)(dir ? 30 : 1) * 8192 + xoff0 + q * 2048);
    __syncthreads();

#define LSTM_STEP(T, XV, PR, PW)                                                       \
    {                                                                                  \
        short8 afr[4];                                                                 \
        _Pragma("unroll")                                                              \
        for (int kf = 0; kf < 4; ++kf)                                                 \
            afr[kf] = *(const short8*)&h_lds[PR][lrow * 136 + kf * 32 + kg * 8];       \
        f32x4 accA[4], accB[4];                                                        \
        _Pragma("unroll")                                                              \
        for (int q = 0; q < 4; ++q) {                                                  \
            f32x4 ci_;                                                                 \
            ci_[0] = bf2f(XV[q][0]); ci_[1] = bf2f(XV[q][1]);                          \
            ci_[2] = bf2f(XV[q][2]); ci_[3] = bf2f(XV[q][3]);                          \
            accA[q] = __builtin_amdgcn_mfma_f32_16x16x32_bf16(afr[0], bfr[q][0], ci_, 0, 0, 0); \
            f32x4 z_ = {};                                                             \
            accB[q] = __builtin_amdgcn_mfma_f32_16x16x32_bf16(afr[2], bfr[q][2], z_, 0, 0, 0);  \
        }                                                                              \
        _Pragma("unroll")                                                              \
        for (int q = 0; q < 4; ++q) {                                                  \
            accA[q] = __builtin_amdgcn_mfma_f32_16x16x32_bf16(afr[1], bfr[q][1], accA[q], 0, 0, 0); \
            accB[q] = __builtin_amdgcn_mfma_f32_16x16x32_bf16(afr[3], bfr[q][3], accB[q], 0, 0, 0); \
        }                                                                              \
        if (w < 2 && (T) > 0) {   /* FC of h(step T-1), held in afr */                 \
            int txp_ = dir ? 32 - (T) : (T) - 1;                                       \
            f32x4 fa_ = {};                                                            \
            _Pragma("unroll")                                                          \
            for (int kf = 0; kf < 4; ++kf)                                             \
                fa_ = __builtin_amdgcn_mfma_f32_16x16x32_bf16(afr[kf], fcfr[kf], fa_, 0, 0, 0); \
            int tag_ = w * 16 + lrow;                                                  \
            if (tag_ < NT) {                                                           \
                unsigned r01_ = cvt_pk_bf16(fa_[0], fa_[1]);                           \
                unsigned r23_ = cvt_pk_bf16(fa_[2], fa_[3]);                           \
                int rb_ = (txp_ * 16 + kg * 4) * 24 + tag_;                            \
                featsL[rb_]      = (unsigned short)r01_;                               \
                featsL[rb_ + 24] = (unsigned short)(r01_ >> 16);                       \
                featsL[rb_ + 48] = (unsigned short)r23_;                               \
                featsL[rb_ + 72] = (unsigned short)(r23_ >> 16);                       \
            }                                                                          \
        }                                                                              \
        if ((T) + 2 < 32) {                                                            \
            int txn = dir ? 29 - (T) : (T) + 2;                                        \
            _Pragma("unroll")                                                          \
            for (int q = 0; q < 4; ++q)                                                \
                XV[q] = *(const ushort4v*)(xbase + (size_t)txn * 8192 + xoff0 + q * 2048); \
        }                                                                              \
        _Pragma("unroll")                                                              \
        for (int i = 0; i < 4; ++i) {                                                  \
            float gi_ = accA[0][i] + accB[0][i];                                       \
            float gf_ = accA[1][i] + accB[1][i];                                       \
            float gg_ = accA[2][i] + accB[2][i];                                       \
            float go_ = accA[3][i] + accB[3][i];                                       \
            float ef_ = __expf(-gf_);                                                  \
            float sfc_ = c[i] * __builtin_amdgcn_rcpf(1.f + ef_);                      \
            float eg2_ = __expf(2.f * gg_);                                            \
            float ei_ = __expf(-gi_);                                                  \
            float tgsi_ = (eg2_ - 1.f) * __builtin_amdgcn_rcpf((1.f + ei_) * (eg2_ + 1.f)); \
            float cn_ = sfc_ + tgsi_;                                                  \
            c[i] = cn_;                                                                \
            float ec2_ = __expf(2.f * cn_);                                            \
            float eo_ = __expf(-go_);                                                  \
            ho[i] = (ec2_ - 1.f) * __builtin_amdgcn_rcpf((1.f + eo_) * (ec2_ + 1.f));  \
        }                                                                              \
        {                                                                              \
            unsigned r01_ = cvt_pk_bf16(ho[0], ho[1]);                                 \
            unsigned r23_ = cvt_pk_bf16(ho[2], ho[3]);                                 \
            int hb_ = (kg * 4) * 136 + w * 16 + lrow;                                  \
            h_lds[PW][hb_]       = (unsigned short)r01_;                               \
            h_lds[PW][hb_ + 136] = (unsigned short)(r01_ >> 16);                       \
            h_lds[PW][hb_ + 272] = (unsigned short)r23_;                               \
            h_lds[PW][hb_ + 408] = (unsigned short)(r23_ >> 16);                       \
        }                                                                              \
        wg_barrier();                                                                  \
    }

    for (int tt = 0; tt < 16; ++tt) {
        LSTM_STEP(2 * tt,     xA, ((2 * tt) & 1),     (((2 * tt) & 1) ^ 1))
        LSTM_STEP(2 * tt + 1, xB, ((2 * tt + 1) & 1), (((2 * tt + 1) & 1) ^ 1))
    }
#undef LSTM_STEP

    // FC for the final h (in h_lds[0] after step 31)
    if (w < 2) {
        short8 afr[4];
#pragma unroll
        for (int kf = 0; kf < 4; ++kf)
            afr[kf] = *(const short8*)&h_lds[0][lrow * 136 + kf * 32 + kg * 8];
        f32x4 fa = {};
#pragma unroll
        for (int kf = 0; kf < 4; ++kf)
            fa = __builtin_amdgcn_mfma_f32_16x16x32_bf16(afr[kf], fcfr[kf], fa, 0, 0, 0);
        int txl = dir ? 0 : 31;
        int tag = w * 16 + lrow;
        if (tag < NT) {
            unsigned r01 = cvt_pk_bf16(fa[0], fa[1]);
            unsigned r23 = cvt_pk_bf16(fa[2], fa[3]);
            int rb = (txl * 16 + kg * 4) * 24 + tag;
            featsL[rb]      = (unsigned short)r01;
            featsL[rb + 24] = (unsigned short)(r01 >> 16);
            featsL[rb + 48] = (unsigned short)r23;
            featsL[rb + 72] = (unsigned short)(r23 >> 16);
        }
    }
    __syncthreads();
    // coalesced flush (bf16): thread (ftx, fs) copies one 24-bf16 row (48B)
    int ftx = tid >> 4, fs = tid & 15;
    unsigned short* gdst = featsP + (((size_t)dir * 32 + ftx) * 512 + s0 + fs) * 24;
    const unsigned short* lsrc = featsL + (ftx * 16 + fs) * 24;
#pragma unroll
    for (int j = 0; j < 3; ++j)
        ((uint4v*)gdst)[j] = ((const uint4v*)lsrc)[j];
}

// ---------------- CRF helpers ----------------
__device__ __forceinline__ float mm_combine(const unsigned short* Rb, const unsigned short* Tb,
                                            int lane, f32x4 c[2][2])
{
    int lrow = lane & 15, kg = lane >> 4;
    short8 a0 = *(const short8*)(Rb + lrow * 32 + kg * 8);
    short8 a1 = *(const short8*)(Rb + (16 + lrow) * 32 + kg * 8);
    short8 b0 = *(const short8*)(Tb + lrow * 32 + kg * 8);
    short8 b1 = *(const short8*)(Tb + (16 + lrow) * 32 + kg * 8);
    c[0][0] = __builtin_amdgcn_mfma_f32_16x16x32_bf16(a0, b0, c[0][0], 0, 0, 0);
    c[0][1] = __builtin_amdgcn_mfma_f32_16x16x32_bf16(a0, b1, c[0][1], 0, 0, 0);
    c[1][0] = __builtin_amdgcn_mfma_f32_16x16x32_bf16(a1, b0, c[1][0], 0, 0, 0);
    c[1][1] = __builtin_amdgcn_mfma_f32_16x16x32_bf16(a1, b1, c[1][1], 0, 0, 0);
    float mx = 0.f;
#pragma unroll
    for (int ti = 0; ti < 2; ++ti)
#pragma unroll
        for (int tj = 0; tj < 2; ++tj)
#pragma unroll
            for (int i = 0; i < 4; ++i) mx = fmaxf(mx, c[ti][tj][i]);
#pragma unroll
    for (int off = 32; off; off >>= 1) mx = fmaxf(mx, __shfl_xor(mx, off));
    return fmaxf(mx, 1e-30f);
}

__device__ __forceinline__ void write_scaled(unsigned short* outp, bool Rlayout,
                                             int lane, const f32x4 c[2][2], float inv)
{
    int lrow = lane & 15, kg = lane >> 4;
    if (Rlayout) {
#pragma unroll
        for (int ti = 0; ti < 2; ++ti)
#pragma unroll
            for (int tj = 0; tj < 2; ++tj) {
                int cc = tj * 16 + lrow;
#pragma unroll
                for (int i = 0; i < 4; ++i) {
                    int r = ti * 16 + kg * 4 + i;
                    float v = (r < NT && cc < NT) ? c[ti][tj][i] * inv : 0.f;
                    outp[r * 32 + cc] = f2bf(v);
                }
            }
    } else {
#pragma unroll
        for (int ti = 0; ti < 2; ++ti)
#pragma unroll
            for (int tj = 0; tj < 2; ++tj) {
                int cc = tj * 16 + lrow;
                int r0 = ti * 16 + kg * 4;
                ushort4v pk;
#pragma unroll
                for (int i = 0; i < 4; ++i) {
                    int r = r0 + i;
                    float v = (r < NT && cc < NT) ? c[ti][tj][i] * inv : 0.f;
                    pk[i] = f2bf(v);
                }
                *(ushort4v*)(outp + cc * 32 + r0) = pk;
            }
    }
}

// block (b=chain, seg): bf16 featsP -> ef/fl, gold partial, 16 leaves -> seg matrix
__launch_bounds__(256)
__global__ void k_fcrf(const unsigned short* featsP, const float* fcb, const float* trans,
                       const int* Y, unsigned short* Mseg, float* lscseg, float* goldp)
{
    __shared__ unsigned short mats[16 * 1024];
    __shared__ float etR[484], etT[484];
    __shared__ float ef[16 * 24];
    __shared__ float fl[16 * 24];
    __shared__ float lscm[16];
    int b = blockIdx.x, seg = blockIdx.y;
    int tid = threadIdx.x;
    int w = tid >> 6, lane = tid & 63;

    for (int i = tid; i < 484; i += 256) {
        float e = __expf(trans[i]);
        etR[i] = e;
        etT[(i % NT) * NT + (i / NT)] = e;
    }
    for (int i = tid; i < 16 * NT; i += 256) {
        int s = i / NT, j = i % NT;
        size_t base = ((size_t)b * 512 + seg * 16 + s) * 24 + j;
        float f = bf2f(featsP[base]) + bf2f(featsP[(size_t)32 * 512 * 24 + base]) + fcb[j];
        fl[s * 24 + j] = f;
        ef[s * 24 + j] = __expf(f);
    }
    if (tid < 16) lscm[tid] = 0.f;
    __syncthreads();

    if (w == 3 && lane < 16) {
        int sg = seg * 16 + lane;
        int y = Y[b * NS + sg];
        int yp = sg ? Y[b * NS + sg - 1] : (NT - 2);
        float gp = fl[lane * 24 + y] + trans[y * NT + yp];
#pragma unroll
        for (int off = 8; off; off >>= 1) gp += __shfl_xor(gp, off);
        if (lane == 0) goldp[b * 32 + seg] = gp;
    }

    // vectorized leaf build: 2 bf16 per thread-iter
    for (int u = tid; u < 16 * 512; u += 256) {
        int t = u >> 9, cell2 = u & 511, row = cell2 >> 4, col = (cell2 & 15) * 2;
        float v0 = 0.f, v1 = 0.f;
        if (row < NT) {
            if (t & 1) {
                if (col < NT)     v0 = etR[row * NT + col]     * ef[t * 24 + row];
                if (col + 1 < NT) v1 = etR[row * NT + col + 1] * ef[t * 24 + row];
            } else {
                if (col < NT)     v0 = etT[row * NT + col]     * ef[t * 24 + col];
                if (col + 1 < NT) v1 = etT[row * NT + col + 1] * ef[t * 24 + col + 1];
            }
        }
        ((unsigned*)mats)[u] = (unsigned)f2bf(v0) | ((unsigned)f2bf(v1) << 16);
    }
    __syncthreads();

    for (int lvl = 0; lvl < 4; ++lvl) {
        int nP = 8 >> lvl;
        for (int p = w; p < nP; p += 4) {
            int aslot = (2 * p) << lvl, bslot = (2 * p + 1) << lvl;
            f32x4 c[2][2] = {};
            float mx = mm_combine(mats + bslot * 1024, mats + aslot * 1024, lane, c);
            float inv = __builtin_amdgcn_rcpf(mx);
            float nlsc = lscm[aslot] + lscm[bslot] + __logf(mx);
            if (lvl < 3) {
                write_scaled(mats + aslot * 1024, (p & 1) != 0, lane, c, inv);
                if (lane == 0) lscm[aslot] = nlsc;
            } else {
                write_scaled(Mseg + ((size_t)b * 32 + seg) * 1024, (seg & 1) != 0, lane, c, inv);
                if (lane == 0) lscseg[b * 32 + seg] = nlsc;
            }
        }
        __syncthreads();
    }
}

// final stage fused: 32 matrices -> score; last finished block writes out[0]
__launch_bounds__(256)
__global__ void k_crf2(const unsigned short* Mseg, const float* lscseg,
                       const float* trans, const int* Y, const float* goldp,
                       float* fwd_sc, float* gold_sc, unsigned* done_cnt, float* out)
{
    __shared__ unsigned short mats[16 * 1024];
    __shared__ float lscm[16];
    __shared__ float tl[484];
    __shared__ float col20[32];
    __shared__ unsigned lastflag;
    int b = blockIdx.x;
    int tid = threadIdx.x;
    int w = tid >> 6, lane = tid & 63;
    int lrow = lane & 15, kg = lane >> 4;

    for (int i = tid; i < 484; i += 256) tl[i] = trans[i];
    __syncthreads();

    const unsigned short* base = Mseg + (size_t)b * 32 * 1024;
    for (int p = w; p < 16; p += 4) {
        f32x4 c[2][2] = {};
        float mx = mm_combine(base + (2 * p + 1) * 1024, base + (2 * p) * 1024, lane, c);
        float inv = __builtin_amdgcn_rcpf(mx);
        float nlsc = lscseg[b * 32 + 2 * p] + lscseg[b * 32 + 2 * p + 1] + __logf(mx);
        write_scaled(mats + p * 1024, (p & 1) != 0, lane, c, inv);
        if (lane == 0) lscm[p] = nlsc;
    }
    __syncthreads();

    for (int lvl = 0; lvl < 4; ++lvl) {
        int nP = 8 >> lvl;
        for (int p = w; p < nP; p += 4) {
            int aslot = (2 * p) << lvl, bslot = (2 * p + 1) << lvl;
            f32x4 c[2][2] = {};
            float mx = mm_combine(mats + bslot * 1024, mats + aslot * 1024, lane, c);
            if (lvl < 3) {
                float inv = __builtin_amdgcn_rcpf(mx);
                float nlsc = lscm[aslot] + lscm[bslot] + __logf(mx);
                write_scaled(mats + aslot * 1024, (p & 1) != 0, lane, c, inv);
                if (lane == 0) lscm[aslot] = nlsc;
            } else {
                if (lrow == 4) {
#pragma unroll
                    for (int ti = 0; ti < 2; ++ti)
#pragma unroll
                        for (int i = 0; i < 4; ++i)
                            col20[ti * 16 + kg * 4 + i] = c[ti][1][i];
                }
                if (lane == 0) lscm[0] = lscm[0] + lscm[8];
            }
        }
        __syncthreads();
    }

    if (w == 0) {
        float v = 0.f;
        if (lane < NT) v = __expf(tl[(NT - 1) * NT + lane]) * col20[lane];
#pragma unroll
        for (int off = 32; off; off >>= 1) v += __shfl_xor(v, off);
        if (lane == 0) fwd_sc[b] = __logf(v) + lscm[0];
    }
    if (w == 1) {
        float g = (lane < 32) ? goldp[b * 32 + lane] : 0.f;
#pragma unroll
        for (int off = 16; off; off >>= 1) g += __shfl_xor(g, off);
        if (lane == 0) gold_sc[b] = g + tl[(NT - 1) * NT + Y[b * NS + NS - 1]];
    }
    // completion: last block computes the mean
    __syncthreads();
    if (tid == 0) {
        __threadfence();
        lastflag = (atomicAdd(done_cnt, 1u) == 31u) ? 1u : 0u;
    }
    __syncthreads();
    if (lastflag && w == 0) {
        __threadfence();
        float v = (lane < NB) ? (fwd_sc[lane] - gold_sc[lane]) : 0.f;
#pragma unroll
        for (int off = 32; off; off >>= 1) v += __shfl_xor(v, off);
        if (lane == 0) out[0] = v * (1.f / NB);
    }
}

extern "C" void kernel_launch(void* const* d_in, const int* in_sizes, int n_in,
                              void* d_out, int out_size, void* d_ws, size_t ws_size,
                              hipStream_t stream)
{
    const int* X = (const int*)d_in[0];
    const int* Y = (const int*)d_in[1];
    const float* emb = (const float*)d_in[2];
    const float* Wih_f = (const float*)d_in[3];
    const float* Whh_f = (const float*)d_in[4];
    const float* bih_f = (const float*)d_in[5];
    const float* bhh_f = (const float*)d_in[6];
    const float* Wih_b = (const float*)d_in[7];
    const float* Whh_b = (const float*)d_in[8];
    const float* bih_b = (const float*)d_in[9];
    const float* bhh_b = (const float*)d_in[10];
    const float* fcW = (const float*)d_in[11];
    const float* fcb = (const float*)d_in[12];
    const float* trans = (const float*)d_in[13];
    const float* h0 = (const float*)d_in[14];
    const float* c0 = (const float*)d_in[15];
    float* out = (float*)d_out;

    char* ws = (char*)d_ws;
    unsigned short* Wb_ih  = (unsigned short*)(ws + 0);          // 524288 B
    unsigned short* Wb_hh  = (unsigned short*)(ws + 524288);     // 262144 B
    unsigned short* fcpad  = (unsigned short*)(ws + 786432);     // 16384 B
    unsigned short* Xp     = (unsigned short*)(ws + 802816);     // 33554432 B
    unsigned short* featsP = (unsigned short*)(ws + 34357248);   // 1572864 B (bf16)
    float* goldp           = (float*)(ws + 35930112);            // 4096 B
    float* fwd_sc          = (float*)(ws + 35934208);            // 128 B
    float* gold_sc         = (float*)(ws + 35934336);            // 128 B
    unsigned* done_cnt     = (unsigned*)(ws + 35934464);         // 128 B
    unsigned short* ebf    = (unsigned short*)(ws + 35934592);   // 8388608 B
    unsigned short* Mseg   = ebf;                                // (ebf dead after k_xproj)
    float* lscseg          = (float*)(ws + 44323200);            // 4096 B (total ~44.3 MB)

    k_pre<<<dim3(5728), dim3(256), 0, stream>>>(X, emb, Y, Wih_f, Wih_b, Whh_f, Whh_b,
                                                fcW, ebf, Wb_ih, Wb_hh, fcpad, out, done_cnt);
    k_xproj<<<dim3(128, 4, 2), dim3(256), 0, stream>>>(ebf, Wb_ih, bih_f, bhh_f, bih_b, bhh_b, Xp);
    k_lstm<<<dim3(64), dim3(512), 0, stream>>>(Wb_hh, fcpad, Xp, h0, c0, featsP);
    k_fcrf<<<dim3(32, 32), dim3(256), 0, stream>>>(featsP, fcb, trans, Y, Mseg, lscseg, goldp);
    k_crf2<<<dim3(NB), dim3(256), 0, stream>>>(Mseg, lscseg, trans, Y, goldp,
                                               fwd_sc, gold_sc, done_cnt, out);
    (void)in_sizes; (void)n_in; (void)out_size; (void)ws_size;
}